// Round 5
// baseline (125.304 us; speedup 1.0000x reference)
//
#include <hip/hip_runtime.h>

#define IS2 0.7071067811865476f
#define C3F 0.35355339059327373f   // (1/sqrt(2))^3
#define TAU_F 0.05f

// ------------------------------------------------------------------
// 2D multilevel Haar (8x8), matches reference _haar2_fwd / _haar2_inv
// ------------------------------------------------------------------
__device__ __forceinline__ void haar2_fwd(float (&m)[64]) {
    float t[64];
    #pragma unroll
    for (int half = 4; half >= 1; half >>= 1) {
        const int sz = half * 2;
        #pragma unroll
        for (int r = 0; r < half; ++r)
            #pragma unroll
            for (int c = 0; c < sz; ++c) {
                float a = m[(2*r)*8 + c], b = m[(2*r+1)*8 + c];
                t[r*8 + c]        = (a + b) * IS2;
                t[(r+half)*8 + c] = (a - b) * IS2;
            }
        #pragma unroll
        for (int r = 0; r < sz; ++r)
            #pragma unroll
            for (int c = 0; c < sz; ++c) m[r*8+c] = t[r*8+c];
        #pragma unroll
        for (int r = 0; r < sz; ++r)
            #pragma unroll
            for (int c = 0; c < half; ++c) {
                float a = m[r*8 + 2*c], b = m[r*8 + 2*c + 1];
                t[r*8 + c]        = (a + b) * IS2;
                t[r*8 + c + half] = (a - b) * IS2;
            }
        #pragma unroll
        for (int r = 0; r < sz; ++r)
            #pragma unroll
            for (int c = 0; c < sz; ++c) m[r*8+c] = t[r*8+c];
    }
}

__device__ __forceinline__ void haar2_inv(float (&m)[64]) {
    float t[64];
    #pragma unroll
    for (int sz = 2; sz <= 8; sz <<= 1) {
        const int half = sz >> 1;
        #pragma unroll
        for (int r = 0; r < sz; ++r)
            #pragma unroll
            for (int c = 0; c < half; ++c) {
                float lo = m[r*8 + c], hi = m[r*8 + c + half];
                t[r*8 + 2*c]     = (lo + hi) * IS2;
                t[r*8 + 2*c + 1] = (lo - hi) * IS2;
            }
        #pragma unroll
        for (int r = 0; r < sz; ++r)
            #pragma unroll
            for (int c = 0; c < sz; ++c) m[r*8+c] = t[r*8+c];
        #pragma unroll
        for (int r = 0; r < half; ++r)
            #pragma unroll
            for (int c = 0; c < sz; ++c) {
                float lo = m[r*8 + c], hi = m[(r+half)*8 + c];
                t[(2*r)*8 + c]   = (lo + hi) * IS2;
                t[(2*r+1)*8 + c] = (lo - hi) * IS2;
            }
        #pragma unroll
        for (int r = 0; r < sz; ++r)
            #pragma unroll
            for (int c = 0; c < sz; ++c) m[r*8+c] = t[r*8+c];
    }
}

// fwd -> soft-threshold (keep DC) -> inv on one 8x8 slice, in registers
__device__ __forceinline__ void bandlet_slice(float (&m)[64]) {
    haar2_fwd(m);
    float dc = m[0];
    #pragma unroll
    for (int e = 0; e < 64; ++e) {
        float v = m[e];
        float av = fabsf(v) - TAU_F;
        m[e] = av > 0.0f ? copysignf(av, v) : 0.0f;
    }
    m[0] = dc;
    haar2_inv(m);
}

// ------------------------------------------------------------------
// Phased bandlet core: PLAIN layout L[i*64 + j*8 + k], stride 516.
// A = LDS accumulator block (same layout). Only ONE m[64] live at a
// time -> no spills (vs round-4's 192-float liveness at barriers).
// Ends with outv = N0_result + acc (UNscaled). No trailing barrier;
// caller must barrier before reusing L or A.
// Must be called by ALL threads (barriers inside).
// ------------------------------------------------------------------
__device__ __forceinline__ void bandlet_phased(float* __restrict__ L,
                                               float* __restrict__ A,
                                               int s, bool valid,
                                               float (&outv)[64]) {
    // ---- Phase A: N2  M[r][c] = blk[r][c][s]; write result to acc ----
    {
        float m[64];
        if (valid) {
            #pragma unroll
            for (int r = 0; r < 8; ++r)
                #pragma unroll
                for (int c = 0; c < 8; ++c)
                    m[r*8+c] = L[r*64 + c*8 + s];
            bandlet_slice(m);
            #pragma unroll
            for (int r = 0; r < 8; ++r)
                #pragma unroll
                for (int c = 0; c < 8; ++c)
                    A[r*64 + c*8 + s] = m[r*8+c];
        }
    }
    __syncthreads();
    // ---- Phase B: N1  M[r][c] = blk[r][s][c]; acc += result (rows) ----
    {
        float m[64];
        if (valid) {
            #pragma unroll
            for (int r = 0; r < 8; ++r) {
                float4 v0 = *(const float4*)&L[r*64 + s*8];
                float4 v1 = *(const float4*)&L[r*64 + s*8 + 4];
                m[r*8+0]=v0.x; m[r*8+1]=v0.y; m[r*8+2]=v0.z; m[r*8+3]=v0.w;
                m[r*8+4]=v1.x; m[r*8+5]=v1.y; m[r*8+6]=v1.z; m[r*8+7]=v1.w;
            }
            bandlet_slice(m);
            #pragma unroll
            for (int r = 0; r < 8; ++r) {
                float4 u0 = *(const float4*)&A[r*64 + s*8];
                float4 u1 = *(const float4*)&A[r*64 + s*8 + 4];
                u0.x+=m[r*8+0]; u0.y+=m[r*8+1]; u0.z+=m[r*8+2]; u0.w+=m[r*8+3];
                u1.x+=m[r*8+4]; u1.y+=m[r*8+5]; u1.z+=m[r*8+6]; u1.w+=m[r*8+7];
                *(float4*)&A[r*64 + s*8]     = u0;
                *(float4*)&A[r*64 + s*8 + 4] = u1;
            }
        }
    }
    __syncthreads();
    // ---- Phase C: N0  M[r][c] = blk[s][r][c]; outv = result + acc ----
    if (valid) {
        #pragma unroll
        for (int r = 0; r < 8; ++r) {
            float4 v0 = *(const float4*)&L[s*64 + r*8];
            float4 v1 = *(const float4*)&L[s*64 + r*8 + 4];
            outv[r*8+0]=v0.x; outv[r*8+1]=v0.y; outv[r*8+2]=v0.z; outv[r*8+3]=v0.w;
            outv[r*8+4]=v1.x; outv[r*8+5]=v1.y; outv[r*8+6]=v1.z; outv[r*8+7]=v1.w;
        }
        bandlet_slice(outv);
        #pragma unroll
        for (int r = 0; r < 8; ++r) {
            float4 v0 = *(const float4*)&A[s*64 + r*8];
            float4 v1 = *(const float4*)&A[s*64 + r*8 + 4];
            outv[r*8+0]+=v0.x; outv[r*8+1]+=v0.y; outv[r*8+2]+=v0.z; outv[r*8+3]+=v0.w;
            outv[r*8+4]+=v1.x; outv[r*8+5]+=v1.y; outv[r*8+6]+=v1.z; outv[r*8+7]+=v1.w;
        }
    }
}

// ------------------------------------------------------------------
// Kernel A: fused level-1 forward DWT + level-1 blockproc.
// One wg (64 thr) = one 16^3 input tile. Grid: 2*10^3 = 2000 wgs.
// LDS: lin 7*516 + acc 7*516 = 28.9 KB -> 5 wg/CU.
// ------------------------------------------------------------------
__global__ __launch_bounds__(64, 2) void fwd1_bp(const float* __restrict__ x,
                                                 float* __restrict__ bands) {
    constexpr int LST = 516;
    constexpr size_t B1S = (size_t)2 * 80 * 80 * 80;
    __shared__ __align__(16) float lin[7 * LST];
    __shared__ __align__(16) float lacc[7 * LST];

    const int t  = threadIdx.x;
    const int wg = blockIdx.x;
    const int b  = wg / 1000;
    const int tl = wg - b * 1000;
    const int td = tl / 100;
    const int rr = tl - td * 100;
    const int th = rr / 10;
    const int tw = rr - th * 10;
    const int j = t >> 3, w = t & 7;

    const float* ip = x + ((size_t)(b*160 + 16*td)) * 25600 + (size_t)(16*th) * 160 + 16*tw;
    float* lllp = bands + ((size_t)(b*80 + 8*td)) * 6400 + (size_t)(8*th) * 80 + 8*tw;

    // ---- phase 1: level-1 forward, voxel (d=q, h=j, w=w) of the tile ----
    #pragma unroll
    for (int q = 0; q < 8; ++q) {
        const float* p = ip + (size_t)(2*q) * 25600 + (2*j) * 160 + 2*w;
        float2 q00 = *(const float2*)(p);
        float2 q01 = *(const float2*)(p + 160);
        float2 q10 = *(const float2*)(p + 25600);
        float2 q11 = *(const float2*)(p + 25600 + 160);
        float wl00 = q00.x + q00.y, wh00 = q00.x - q00.y;
        float wl01 = q01.x + q01.y, wh01 = q01.x - q01.y;
        float wl10 = q10.x + q10.y, wh10 = q10.x - q10.y;
        float wl11 = q11.x + q11.y, wh11 = q11.x - q11.y;
        float hl0l = wl00 + wl01, hh0l = wl00 - wl01;
        float hl0h = wh00 + wh01, hh0h = wh00 - wh01;
        float hl1l = wl10 + wl11, hh1l = wl10 - wl11;
        float hl1h = wh10 + wh11, hh1h = wh10 - wh11;
        const int pos = q*64 + j*8 + w;               // PLAIN layout
        lin[0*LST + pos] = (hl0h + hl1h) * C3F;   // band 1 llh
        lin[1*LST + pos] = (hh0l + hh1l) * C3F;   // band 2 lhl
        lin[2*LST + pos] = (hh0h + hh1h) * C3F;   // band 3 lhh
        lin[3*LST + pos] = (hl0l - hl1l) * C3F;   // band 4 hll
        lin[4*LST + pos] = (hl0h - hl1h) * C3F;   // band 5 hlh
        lin[5*LST + pos] = (hh0l - hh1l) * C3F;   // band 6 hhl
        lin[6*LST + pos] = (hh0h - hh1h) * C3F;   // band 7 hhh
        lllp[q*6400 + j*80 + w] = (hl0l + hl1l) * C3F;   // band 0 lll (raw)
    }
    __syncthreads();

    // ---- phase 2: phased blockproc of the 7 band blocks ----
    const int nbp = t >> 3, s = t & 7;
    const bool valid = nbp < 7;
    const int off = (valid ? nbp : 0) * LST;
    float outv[64];
    bandlet_phased(&lin[off], &lacc[off], s, valid, outv);

    // ---- phase 3: stage-out processed band (nbp+1), slice d=s ----
    if (valid) {
        float* gp = bands + (size_t)(nbp + 1) * B1S
                  + ((size_t)(b*80 + 8*td + s)) * 6400 + (size_t)(8*th) * 80 + 8*tw;
        #pragma unroll
        for (int jj = 0; jj < 8; ++jj) {
            float* qo = gp + jj * 80;
            *(float4*)(qo)     = make_float4(outv[jj*8+0]*(1.0f/3.0f), outv[jj*8+1]*(1.0f/3.0f),
                                             outv[jj*8+2]*(1.0f/3.0f), outv[jj*8+3]*(1.0f/3.0f));
            *(float4*)(qo + 4) = make_float4(outv[jj*8+4]*(1.0f/3.0f), outv[jj*8+5]*(1.0f/3.0f),
                                             outv[jj*8+6]*(1.0f/3.0f), outv[jj*8+7]*(1.0f/3.0f));
        }
    }
}

// ------------------------------------------------------------------
// Kernel B: fused level-2 forward + blockproc + level-2 inverse,
// in place on lll1 (= bands[0]). One wg = one 16^3 tile. 250 wgs.
// LDS: lin 8*516 + acc 7*516 = 31 KB.
// ------------------------------------------------------------------
__global__ __launch_bounds__(64, 2) void l2_pipeline(float* __restrict__ lll) {
    constexpr int LST = 516;
    __shared__ __align__(16) float lin[8 * LST];
    __shared__ __align__(16) float lacc[7 * LST];

    const int t  = threadIdx.x;
    const int wg = blockIdx.x;
    const int b  = wg / 125;
    const int tl = wg - b * 125;
    const int td = tl / 25;
    const int rr = tl - td * 25;
    const int th = rr / 5;
    const int tw = rr - th * 5;
    const int j = t >> 3, w = t & 7;

    float* base = lll + ((size_t)(b*80 + 16*td)) * 6400 + (size_t)(16*th) * 80 + 16*tw;

    // ---- phase 1: level-2 forward, all 8 bands into LDS ----
    #pragma unroll
    for (int q = 0; q < 8; ++q) {
        const float* p = base + (size_t)(2*q) * 6400 + (2*j) * 80 + 2*w;
        float2 q00 = *(const float2*)(p);
        float2 q01 = *(const float2*)(p + 80);
        float2 q10 = *(const float2*)(p + 6400);
        float2 q11 = *(const float2*)(p + 6400 + 80);
        float wl00 = q00.x + q00.y, wh00 = q00.x - q00.y;
        float wl01 = q01.x + q01.y, wh01 = q01.x - q01.y;
        float wl10 = q10.x + q10.y, wh10 = q10.x - q10.y;
        float wl11 = q11.x + q11.y, wh11 = q11.x - q11.y;
        float hl0l = wl00 + wl01, hh0l = wl00 - wl01;
        float hl0h = wh00 + wh01, hh0h = wh00 - wh01;
        float hl1l = wl10 + wl11, hh1l = wl10 - wl11;
        float hl1h = wh10 + wh11, hh1h = wh10 - wh11;
        const int pos = q*64 + j*8 + w;               // PLAIN layout
        lin[0*LST + pos] = (hl0l + hl1l) * C3F;   // lll2 (kept unprocessed)
        lin[1*LST + pos] = (hl0h + hl1h) * C3F;
        lin[2*LST + pos] = (hh0l + hh1l) * C3F;
        lin[3*LST + pos] = (hh0h + hh1h) * C3F;
        lin[4*LST + pos] = (hl0l - hl1l) * C3F;
        lin[5*LST + pos] = (hl0h - hl1h) * C3F;
        lin[6*LST + pos] = (hh0l - hh1l) * C3F;
        lin[7*LST + pos] = (hh0h - hh1h) * C3F;
    }
    __syncthreads();

    // ---- phase 2: phased blockproc bands 1..7 (buffer 0 untouched) ----
    const int nbp = t >> 3, s = t & 7;
    const bool valid = nbp < 7;
    float outv[64];
    bandlet_phased(&lin[(valid ? nbp + 1 : 1) * LST],
                   &lacc[(valid ? nbp : 0) * LST], s, valid, outv);

    __syncthreads();   // phase-C lin reads drained before write-back
    if (valid) {
        float* L = &lin[(nbp + 1) * LST];
        #pragma unroll
        for (int jj = 0; jj < 8; ++jj) {
            *(float4*)&L[s*64 + jj*8]     = make_float4(outv[jj*8+0]*(1.0f/3.0f), outv[jj*8+1]*(1.0f/3.0f),
                                                        outv[jj*8+2]*(1.0f/3.0f), outv[jj*8+3]*(1.0f/3.0f));
            *(float4*)&L[s*64 + jj*8 + 4] = make_float4(outv[jj*8+4]*(1.0f/3.0f), outv[jj*8+5]*(1.0f/3.0f),
                                                        outv[jj*8+6]*(1.0f/3.0f), outv[jj*8+7]*(1.0f/3.0f));
        }
    }
    __syncthreads();

    // ---- phase 3: level-2 inverse, write back in place ----
    #pragma unroll
    for (int q = 0; q < 8; ++q) {
        const int pos = q*64 + j*8 + w;               // PLAIN layout
        float b0 = lin[0*LST + pos], b1 = lin[1*LST + pos];
        float b2 = lin[2*LST + pos], b3 = lin[3*LST + pos];
        float b4 = lin[4*LST + pos], b5 = lin[5*LST + pos];
        float b6 = lin[6*LST + pos], b7 = lin[7*LST + pos];
        float c0 = b0 + b4, c1 = b1 + b5, c2 = b2 + b6, c3 = b3 + b7;
        float c4 = b0 - b4, c5 = b1 - b5, c6 = b2 - b6, c7 = b3 - b7;
        float e00 = c0 + c2, e01 = c1 + c3;
        float e02 = c0 - c2, e03 = c1 - c3;
        float e10 = c4 + c6, e11 = c5 + c7;
        float e12 = c4 - c6, e13 = c5 - c7;
        float* pp = base + (size_t)(2*q) * 6400 + (2*j) * 80 + 2*w;
        *(float2*)(pp)             = make_float2((e00+e01)*C3F, (e00-e01)*C3F);
        *(float2*)(pp + 80)        = make_float2((e02+e03)*C3F, (e02-e03)*C3F);
        *(float2*)(pp + 6400)      = make_float2((e10+e11)*C3F, (e10-e11)*C3F);
        *(float2*)(pp + 6400 + 80) = make_float2((e12+e13)*C3F, (e12-e13)*C3F);
    }
}

// ------------------------------------------------------------------
// Kernel C: level-1 inverse, 8 bands (2,80^3) -> out (2,160^3).
// One thread = 2 adjacent w voxels: float2 loads, float4 stores.
// ------------------------------------------------------------------
__global__ __launch_bounds__(256) void dwt3_inv80(const float* __restrict__ bands,
                                                  float* __restrict__ out) {
    const int tid = blockIdx.x * blockDim.x + threadIdx.x;
    constexpr int S = 80, S2 = S / 2;
    const int w2 = tid % S2;
    const int h  = (tid / S2) % S;
    const int d  = (tid / (S2*S)) % S;
    const int b  = tid / (S2*S*S);
    constexpr size_t bs_ = (size_t)2 * S * S * S;
    const size_t o = (((size_t)b * S + d) * S + h) * S + 2*w2;

    float2 B0 = *(const float2*)&bands[0*bs_+o], B1 = *(const float2*)&bands[1*bs_+o];
    float2 B2 = *(const float2*)&bands[2*bs_+o], B3 = *(const float2*)&bands[3*bs_+o];
    float2 B4 = *(const float2*)&bands[4*bs_+o], B5 = *(const float2*)&bands[5*bs_+o];
    float2 B6 = *(const float2*)&bands[6*bs_+o], B7 = *(const float2*)&bands[7*bs_+o];

    constexpr int IS = 2 * S;
    float* p = out + (((size_t)b * IS + 2*d) * IS + 2*h) * IS + 4*w2;

    #pragma unroll
    for (int half = 0; half < 2; ++half) {
        float b0 = half ? B0.y : B0.x, b1 = half ? B1.y : B1.x;
        float b2 = half ? B2.y : B2.x, b3 = half ? B3.y : B3.x;
        float b4 = half ? B4.y : B4.x, b5 = half ? B5.y : B5.x;
        float b6 = half ? B6.y : B6.x, b7 = half ? B7.y : B7.x;
        float c0 = b0 + b4, c1 = b1 + b5, c2 = b2 + b6, c3 = b3 + b7;
        float c4 = b0 - b4, c5 = b1 - b5, c6 = b2 - b6, c7 = b3 - b7;
        float e00 = c0 + c2, e01 = c1 + c3;
        float e02 = c0 - c2, e03 = c1 - c3;
        float e10 = c4 + c6, e11 = c5 + c7;
        float e12 = c4 - c6, e13 = c5 - c7;
        const int xo = 2 * half;
        // row (2d, 2h): even/odd w
        ((float2*)(p))[half]                      = make_float2((e00+e01)*C3F, (e00-e01)*C3F);
        ((float2*)(p + IS))[half]                 = make_float2((e02+e03)*C3F, (e02-e03)*C3F);
        ((float2*)(p + (size_t)IS*IS))[half]      = make_float2((e10+e11)*C3F, (e10-e11)*C3F);
        ((float2*)(p + (size_t)IS*IS + IS))[half] = make_float2((e12+e13)*C3F, (e12-e13)*C3F);
        (void)xo;
    }
}

// ------------------------------------------------------------------
// Pipeline (3 launches):
//   A: x (2,160^3) -> bands[0]=lll1 raw, bands[1..7] processed   [d_ws]
//   B: bands[0] -> fwd2 + blockproc + inv2, in place (LDS-resident)
//   C: bands[0..7] -> inverse level-1 -> d_out
// ------------------------------------------------------------------
extern "C" void kernel_launch(void* const* d_in, const int* in_sizes, int n_in,
                              void* d_out, int out_size, void* d_ws, size_t ws_size,
                              hipStream_t stream) {
    const float* x = (const float*)d_in[0];
    float* out = (float*)d_out;
    float* bands = (float*)d_ws;   // 8 * 2*80^3 floats = 32.77 MB

    fwd1_bp<<<2000, 64, 0, stream>>>(x, bands);
    l2_pipeline<<<250, 64, 0, stream>>>(bands);
    // 2*80*80*80/2 threads = 512000 -> 2000 wgs of 256
    dwt3_inv80<<<2000, 256, 0, stream>>>(bands, out);
}

// Round 6
// 123.985 us; speedup vs baseline: 1.0106x; 1.0106x over previous
//
#include <hip/hip_runtime.h>

#define IS2 0.7071067811865476f
#define C3F 0.35355339059327373f   // (1/sqrt(2))^3
#define TAU_F 0.05f

// ------------------------------------------------------------------
// 2D multilevel Haar (8x8), matches reference _haar2_fwd / _haar2_inv
// ------------------------------------------------------------------
__device__ __forceinline__ void haar2_fwd(float (&m)[64]) {
    float t[64];
    #pragma unroll
    for (int half = 4; half >= 1; half >>= 1) {
        const int sz = half * 2;
        #pragma unroll
        for (int r = 0; r < half; ++r)
            #pragma unroll
            for (int c = 0; c < sz; ++c) {
                float a = m[(2*r)*8 + c], b = m[(2*r+1)*8 + c];
                t[r*8 + c]        = (a + b) * IS2;
                t[(r+half)*8 + c] = (a - b) * IS2;
            }
        #pragma unroll
        for (int r = 0; r < sz; ++r)
            #pragma unroll
            for (int c = 0; c < sz; ++c) m[r*8+c] = t[r*8+c];
        #pragma unroll
        for (int r = 0; r < sz; ++r)
            #pragma unroll
            for (int c = 0; c < half; ++c) {
                float a = m[r*8 + 2*c], b = m[r*8 + 2*c + 1];
                t[r*8 + c]        = (a + b) * IS2;
                t[r*8 + c + half] = (a - b) * IS2;
            }
        #pragma unroll
        for (int r = 0; r < sz; ++r)
            #pragma unroll
            for (int c = 0; c < sz; ++c) m[r*8+c] = t[r*8+c];
    }
}

__device__ __forceinline__ void haar2_inv(float (&m)[64]) {
    float t[64];
    #pragma unroll
    for (int sz = 2; sz <= 8; sz <<= 1) {
        const int half = sz >> 1;
        #pragma unroll
        for (int r = 0; r < sz; ++r)
            #pragma unroll
            for (int c = 0; c < half; ++c) {
                float lo = m[r*8 + c], hi = m[r*8 + c + half];
                t[r*8 + 2*c]     = (lo + hi) * IS2;
                t[r*8 + 2*c + 1] = (lo - hi) * IS2;
            }
        #pragma unroll
        for (int r = 0; r < sz; ++r)
            #pragma unroll
            for (int c = 0; c < sz; ++c) m[r*8+c] = t[r*8+c];
        #pragma unroll
        for (int r = 0; r < half; ++r)
            #pragma unroll
            for (int c = 0; c < sz; ++c) {
                float lo = m[r*8 + c], hi = m[(r+half)*8 + c];
                t[(2*r)*8 + c]   = (lo + hi) * IS2;
                t[(2*r+1)*8 + c] = (lo - hi) * IS2;
            }
        #pragma unroll
        for (int r = 0; r < sz; ++r)
            #pragma unroll
            for (int c = 0; c < sz; ++c) m[r*8+c] = t[r*8+c];
    }
}

// fwd -> soft-threshold (keep DC) -> inv on one 8x8 slice, in registers
__device__ __forceinline__ void bandlet_slice(float (&m)[64]) {
    haar2_fwd(m);
    float dc = m[0];
    #pragma unroll
    for (int e = 0; e < 64; ++e) {
        float v = m[e];
        float av = fabsf(v) - TAU_F;
        m[e] = av > 0.0f ? copysignf(av, v) : 0.0f;
    }
    m[0] = dc;
    haar2_inv(m);
}

// ------------------------------------------------------------------
// Phased bandlet core: PLAIN layout L[i*64 + j*8 + k], stride 516.
// A = LDS accumulator block. Only ONE m[64] live at a time (no spills).
// Ends with outv = N0_result + acc (UNscaled). No trailing barrier.
// Bank check (stride 516 -> base offset 4*nb): b32 ops 2-way (free),
// b128 row ops exactly 8 dwords/bank (free).
// ------------------------------------------------------------------
__device__ __forceinline__ void bandlet_phased(float* __restrict__ L,
                                               float* __restrict__ A,
                                               int s, bool valid,
                                               float (&outv)[64]) {
    // ---- Phase A: N2  M[r][c] = blk[r][c][s]; write result to acc ----
    {
        float m[64];
        if (valid) {
            #pragma unroll
            for (int r = 0; r < 8; ++r)
                #pragma unroll
                for (int c = 0; c < 8; ++c)
                    m[r*8+c] = L[r*64 + c*8 + s];
            bandlet_slice(m);
            #pragma unroll
            for (int r = 0; r < 8; ++r)
                #pragma unroll
                for (int c = 0; c < 8; ++c)
                    A[r*64 + c*8 + s] = m[r*8+c];
        }
    }
    __syncthreads();
    // ---- Phase B: N1  M[r][c] = blk[r][s][c]; acc += result (rows) ----
    {
        float m[64];
        if (valid) {
            #pragma unroll
            for (int r = 0; r < 8; ++r) {
                float4 v0 = *(const float4*)&L[r*64 + s*8];
                float4 v1 = *(const float4*)&L[r*64 + s*8 + 4];
                m[r*8+0]=v0.x; m[r*8+1]=v0.y; m[r*8+2]=v0.z; m[r*8+3]=v0.w;
                m[r*8+4]=v1.x; m[r*8+5]=v1.y; m[r*8+6]=v1.z; m[r*8+7]=v1.w;
            }
            bandlet_slice(m);
            #pragma unroll
            for (int r = 0; r < 8; ++r) {
                float4 u0 = *(const float4*)&A[r*64 + s*8];
                float4 u1 = *(const float4*)&A[r*64 + s*8 + 4];
                u0.x+=m[r*8+0]; u0.y+=m[r*8+1]; u0.z+=m[r*8+2]; u0.w+=m[r*8+3];
                u1.x+=m[r*8+4]; u1.y+=m[r*8+5]; u1.z+=m[r*8+6]; u1.w+=m[r*8+7];
                *(float4*)&A[r*64 + s*8]     = u0;
                *(float4*)&A[r*64 + s*8 + 4] = u1;
            }
        }
    }
    __syncthreads();
    // ---- Phase C: N0  M[r][c] = blk[s][r][c]; outv = result + acc ----
    if (valid) {
        #pragma unroll
        for (int r = 0; r < 8; ++r) {
            float4 v0 = *(const float4*)&L[s*64 + r*8];
            float4 v1 = *(const float4*)&L[s*64 + r*8 + 4];
            outv[r*8+0]=v0.x; outv[r*8+1]=v0.y; outv[r*8+2]=v0.z; outv[r*8+3]=v0.w;
            outv[r*8+4]=v1.x; outv[r*8+5]=v1.y; outv[r*8+6]=v1.z; outv[r*8+7]=v1.w;
        }
        bandlet_slice(outv);
        #pragma unroll
        for (int r = 0; r < 8; ++r) {
            float4 v0 = *(const float4*)&A[s*64 + r*8];
            float4 v1 = *(const float4*)&A[s*64 + r*8 + 4];
            outv[r*8+0]+=v0.x; outv[r*8+1]+=v0.y; outv[r*8+2]+=v0.z; outv[r*8+3]+=v0.w;
            outv[r*8+4]+=v1.x; outv[r*8+5]+=v1.y; outv[r*8+6]+=v1.z; outv[r*8+7]+=v1.w;
        }
    }
}

// ------------------------------------------------------------------
// Kernel A: fused level-1 forward DWT + level-1 blockproc.
// One wg (64 thr) = one 16^3 input tile. Grid: 2000 wgs.
// LDS 28.9 KB -> 5 wg/CU. All 32 phase-1 global loads hoisted into
// registers before the butterfly/LDS writes (one vmcnt drain).
// ------------------------------------------------------------------
__global__ __launch_bounds__(64, 2) void fwd1_bp(const float* __restrict__ x,
                                                 float* __restrict__ bands) {
    constexpr int LST = 516;
    constexpr size_t B1S = (size_t)2 * 80 * 80 * 80;
    __shared__ __align__(16) float lin[7 * LST];
    __shared__ __align__(16) float lacc[7 * LST];

    const int t  = threadIdx.x;
    const int wg = blockIdx.x;
    const int b  = wg / 1000;
    const int tl = wg - b * 1000;
    const int td = tl / 100;
    const int rr = tl - td * 100;
    const int th = rr / 10;
    const int tw = rr - th * 10;
    const int j = t >> 3, w = t & 7;

    const float* ip = x + ((size_t)(b*160 + 16*td)) * 25600 + (size_t)(16*th) * 160 + 16*tw;
    float* lllp = bands + ((size_t)(b*80 + 8*td)) * 6400 + (size_t)(8*th) * 80 + 8*tw;

    // ---- phase 1a: hoist ALL 32 global loads (independent, one drain) ----
    float2 ld[32];
    #pragma unroll
    for (int q = 0; q < 8; ++q) {
        const float* p = ip + (size_t)(2*q) * 25600 + (2*j) * 160 + 2*w;
        ld[q*4+0] = *(const float2*)(p);
        ld[q*4+1] = *(const float2*)(p + 160);
        ld[q*4+2] = *(const float2*)(p + 25600);
        ld[q*4+3] = *(const float2*)(p + 25600 + 160);
    }
    // ---- phase 1b: butterflies + LDS/global writes ----
    #pragma unroll
    for (int q = 0; q < 8; ++q) {
        float2 q00 = ld[q*4+0], q01 = ld[q*4+1], q10 = ld[q*4+2], q11 = ld[q*4+3];
        float wl00 = q00.x + q00.y, wh00 = q00.x - q00.y;
        float wl01 = q01.x + q01.y, wh01 = q01.x - q01.y;
        float wl10 = q10.x + q10.y, wh10 = q10.x - q10.y;
        float wl11 = q11.x + q11.y, wh11 = q11.x - q11.y;
        float hl0l = wl00 + wl01, hh0l = wl00 - wl01;
        float hl0h = wh00 + wh01, hh0h = wh00 - wh01;
        float hl1l = wl10 + wl11, hh1l = wl10 - wl11;
        float hl1h = wh10 + wh11, hh1h = wh10 - wh11;
        const int pos = q*64 + j*8 + w;               // PLAIN layout
        lin[0*LST + pos] = (hl0h + hl1h) * C3F;   // band 1 llh
        lin[1*LST + pos] = (hh0l + hh1l) * C3F;   // band 2 lhl
        lin[2*LST + pos] = (hh0h + hh1h) * C3F;   // band 3 lhh
        lin[3*LST + pos] = (hl0l - hl1l) * C3F;   // band 4 hll
        lin[4*LST + pos] = (hl0h - hl1h) * C3F;   // band 5 hlh
        lin[5*LST + pos] = (hh0l - hh1l) * C3F;   // band 6 hhl
        lin[6*LST + pos] = (hh0h - hh1h) * C3F;   // band 7 hhh
        lllp[q*6400 + j*80 + w] = (hl0l + hl1l) * C3F;   // band 0 lll (raw)
    }
    __syncthreads();

    // ---- phase 2: phased blockproc of the 7 band blocks ----
    const int nbp = t >> 3, s = t & 7;
    const bool valid = nbp < 7;
    const int off = (valid ? nbp : 0) * LST;
    float outv[64];
    bandlet_phased(&lin[off], &lacc[off], s, valid, outv);

    // ---- phase 3: stage-out processed band (nbp+1), slice d=s ----
    if (valid) {
        float* gp = bands + (size_t)(nbp + 1) * B1S
                  + ((size_t)(b*80 + 8*td + s)) * 6400 + (size_t)(8*th) * 80 + 8*tw;
        #pragma unroll
        for (int jj = 0; jj < 8; ++jj) {
            float* qo = gp + jj * 80;
            *(float4*)(qo)     = make_float4(outv[jj*8+0]*(1.0f/3.0f), outv[jj*8+1]*(1.0f/3.0f),
                                             outv[jj*8+2]*(1.0f/3.0f), outv[jj*8+3]*(1.0f/3.0f));
            *(float4*)(qo + 4) = make_float4(outv[jj*8+4]*(1.0f/3.0f), outv[jj*8+5]*(1.0f/3.0f),
                                             outv[jj*8+6]*(1.0f/3.0f), outv[jj*8+7]*(1.0f/3.0f));
        }
    }
}

// ------------------------------------------------------------------
// Kernel B: fused level-2 forward + blockproc + level-2 inverse,
// in place on lll1. One wg = one 16^3 tile. 250 wgs (~1 wave/CU,
// grid-bound) -> launch_bounds(64,1) frees the register allocator;
// all 32 phase-1 loads hoisted (single ~900-cyc drain, not 8).
// ------------------------------------------------------------------
__global__ __launch_bounds__(64, 1) void l2_pipeline(float* __restrict__ lll) {
    constexpr int LST = 516;
    __shared__ __align__(16) float lin[8 * LST];
    __shared__ __align__(16) float lacc[7 * LST];

    const int t  = threadIdx.x;
    const int wg = blockIdx.x;
    const int b  = wg / 125;
    const int tl = wg - b * 125;
    const int td = tl / 25;
    const int rr = tl - td * 25;
    const int th = rr / 5;
    const int tw = rr - th * 5;
    const int j = t >> 3, w = t & 7;

    float* base = lll + ((size_t)(b*80 + 16*td)) * 6400 + (size_t)(16*th) * 80 + 16*tw;

    // ---- phase 1a: hoist all 32 global loads ----
    float2 ld[32];
    #pragma unroll
    for (int q = 0; q < 8; ++q) {
        const float* p = base + (size_t)(2*q) * 6400 + (2*j) * 80 + 2*w;
        ld[q*4+0] = *(const float2*)(p);
        ld[q*4+1] = *(const float2*)(p + 80);
        ld[q*4+2] = *(const float2*)(p + 6400);
        ld[q*4+3] = *(const float2*)(p + 6400 + 80);
    }
    // ---- phase 1b: level-2 forward, all 8 bands into LDS ----
    #pragma unroll
    for (int q = 0; q < 8; ++q) {
        float2 q00 = ld[q*4+0], q01 = ld[q*4+1], q10 = ld[q*4+2], q11 = ld[q*4+3];
        float wl00 = q00.x + q00.y, wh00 = q00.x - q00.y;
        float wl01 = q01.x + q01.y, wh01 = q01.x - q01.y;
        float wl10 = q10.x + q10.y, wh10 = q10.x - q10.y;
        float wl11 = q11.x + q11.y, wh11 = q11.x - q11.y;
        float hl0l = wl00 + wl01, hh0l = wl00 - wl01;
        float hl0h = wh00 + wh01, hh0h = wh00 - wh01;
        float hl1l = wl10 + wl11, hh1l = wl10 - wl11;
        float hl1h = wh10 + wh11, hh1h = wh10 - wh11;
        const int pos = q*64 + j*8 + w;               // PLAIN layout
        lin[0*LST + pos] = (hl0l + hl1l) * C3F;   // lll2 (kept unprocessed)
        lin[1*LST + pos] = (hl0h + hl1h) * C3F;
        lin[2*LST + pos] = (hh0l + hh1l) * C3F;
        lin[3*LST + pos] = (hh0h + hh1h) * C3F;
        lin[4*LST + pos] = (hl0l - hl1l) * C3F;
        lin[5*LST + pos] = (hl0h - hl1h) * C3F;
        lin[6*LST + pos] = (hh0l - hh1l) * C3F;
        lin[7*LST + pos] = (hh0h - hh1h) * C3F;
    }
    __syncthreads();

    // ---- phase 2: phased blockproc bands 1..7 (buffer 0 untouched) ----
    const int nbp = t >> 3, s = t & 7;
    const bool valid = nbp < 7;
    float outv[64];
    bandlet_phased(&lin[(valid ? nbp + 1 : 1) * LST],
                   &lacc[(valid ? nbp : 0) * LST], s, valid, outv);

    __syncthreads();   // phase-C lin reads drained before write-back
    if (valid) {
        float* L = &lin[(nbp + 1) * LST];
        #pragma unroll
        for (int jj = 0; jj < 8; ++jj) {
            *(float4*)&L[s*64 + jj*8]     = make_float4(outv[jj*8+0]*(1.0f/3.0f), outv[jj*8+1]*(1.0f/3.0f),
                                                        outv[jj*8+2]*(1.0f/3.0f), outv[jj*8+3]*(1.0f/3.0f));
            *(float4*)&L[s*64 + jj*8 + 4] = make_float4(outv[jj*8+4]*(1.0f/3.0f), outv[jj*8+5]*(1.0f/3.0f),
                                                        outv[jj*8+6]*(1.0f/3.0f), outv[jj*8+7]*(1.0f/3.0f));
        }
    }
    __syncthreads();

    // ---- phase 3: level-2 inverse, write back in place ----
    #pragma unroll
    for (int q = 0; q < 8; ++q) {
        const int pos = q*64 + j*8 + w;               // PLAIN layout
        float b0 = lin[0*LST + pos], b1 = lin[1*LST + pos];
        float b2 = lin[2*LST + pos], b3 = lin[3*LST + pos];
        float b4 = lin[4*LST + pos], b5 = lin[5*LST + pos];
        float b6 = lin[6*LST + pos], b7 = lin[7*LST + pos];
        float c0 = b0 + b4, c1 = b1 + b5, c2 = b2 + b6, c3 = b3 + b7;
        float c4 = b0 - b4, c5 = b1 - b5, c6 = b2 - b6, c7 = b3 - b7;
        float e00 = c0 + c2, e01 = c1 + c3;
        float e02 = c0 - c2, e03 = c1 - c3;
        float e10 = c4 + c6, e11 = c5 + c7;
        float e12 = c4 - c6, e13 = c5 - c7;
        float* pp = base + (size_t)(2*q) * 6400 + (2*j) * 80 + 2*w;
        *(float2*)(pp)             = make_float2((e00+e01)*C3F, (e00-e01)*C3F);
        *(float2*)(pp + 80)        = make_float2((e02+e03)*C3F, (e02-e03)*C3F);
        *(float2*)(pp + 6400)      = make_float2((e10+e11)*C3F, (e10-e11)*C3F);
        *(float2*)(pp + 6400 + 80) = make_float2((e12+e13)*C3F, (e12-e13)*C3F);
    }
}

// ------------------------------------------------------------------
// Kernel C: level-1 inverse, 8 bands (2,80^3) -> out (2,160^3).
// One thread = 2 adjacent w voxels; 8 independent float2 loads,
// 4 float4 stores (full dwordx4 rows).
// ------------------------------------------------------------------
__global__ __launch_bounds__(256) void dwt3_inv80(const float* __restrict__ bands,
                                                  float* __restrict__ out) {
    const int tid = blockIdx.x * blockDim.x + threadIdx.x;
    constexpr int S = 80, HW = S / 2;
    const int w2 = tid % HW;
    const int h  = (tid / HW) % S;
    const int d  = (tid / (HW*S)) % S;
    const int b  = tid / (HW*S*S);
    constexpr size_t bs_ = (size_t)2 * S * S * S;
    const size_t o = (((size_t)b * S + d) * S + h) * S + 2*w2;

    float2 B[8];
    #pragma unroll
    for (int n = 0; n < 8; ++n) B[n] = *(const float2*)&bands[n*bs_ + o];

    constexpr int IS = 2 * S;
    float* p = out + (((size_t)(b*IS + 2*d)) * IS + 2*h) * IS + 4*w2;

    float4 r0, r1, r2, r3;
    {   // band column 2*w2 -> output x = 4*w2, 4*w2+1
        float c0 = B[0].x + B[4].x, c1 = B[1].x + B[5].x, c2 = B[2].x + B[6].x, c3 = B[3].x + B[7].x;
        float c4 = B[0].x - B[4].x, c5 = B[1].x - B[5].x, c6 = B[2].x - B[6].x, c7 = B[3].x - B[7].x;
        float e00 = c0 + c2, e01 = c1 + c3, e02 = c0 - c2, e03 = c1 - c3;
        float e10 = c4 + c6, e11 = c5 + c7, e12 = c4 - c6, e13 = c5 - c7;
        r0.x = (e00+e01)*C3F; r0.y = (e00-e01)*C3F;
        r1.x = (e02+e03)*C3F; r1.y = (e02-e03)*C3F;
        r2.x = (e10+e11)*C3F; r2.y = (e10-e11)*C3F;
        r3.x = (e12+e13)*C3F; r3.y = (e12-e13)*C3F;
    }
    {   // band column 2*w2+1 -> output x = 4*w2+2, 4*w2+3
        float c0 = B[0].y + B[4].y, c1 = B[1].y + B[5].y, c2 = B[2].y + B[6].y, c3 = B[3].y + B[7].y;
        float c4 = B[0].y - B[4].y, c5 = B[1].y - B[5].y, c6 = B[2].y - B[6].y, c7 = B[3].y - B[7].y;
        float e00 = c0 + c2, e01 = c1 + c3, e02 = c0 - c2, e03 = c1 - c3;
        float e10 = c4 + c6, e11 = c5 + c7, e12 = c4 - c6, e13 = c5 - c7;
        r0.z = (e00+e01)*C3F; r0.w = (e00-e01)*C3F;
        r1.z = (e02+e03)*C3F; r1.w = (e02-e03)*C3F;
        r2.z = (e10+e11)*C3F; r2.w = (e10-e11)*C3F;
        r3.z = (e12+e13)*C3F; r3.w = (e12-e13)*C3F;
    }
    *(float4*)(p)                      = r0;   // row (2d,   2h  )
    *(float4*)(p + IS)                 = r1;   // row (2d,   2h+1)
    *(float4*)(p + (size_t)IS*IS)      = r2;   // row (2d+1, 2h  )
    *(float4*)(p + (size_t)IS*IS + IS) = r3;   // row (2d+1, 2h+1)
}

// ------------------------------------------------------------------
// Pipeline (3 launches):
//   A: x (2,160^3) -> bands[0]=lll1 raw, bands[1..7] processed   [d_ws]
//   B: bands[0] -> fwd2 + blockproc + inv2, in place (LDS-resident)
//   C: bands[0..7] -> inverse level-1 -> d_out
// ------------------------------------------------------------------
extern "C" void kernel_launch(void* const* d_in, const int* in_sizes, int n_in,
                              void* d_out, int out_size, void* d_ws, size_t ws_size,
                              hipStream_t stream) {
    const float* x = (const float*)d_in[0];
    float* out = (float*)d_out;
    float* bands = (float*)d_ws;   // 8 * 2*80^3 floats = 32.77 MB

    fwd1_bp<<<2000, 64, 0, stream>>>(x, bands);
    l2_pipeline<<<250, 64, 0, stream>>>(bands);
    // 2*80^3/2 threads = 512000 -> 2000 wgs of 256
    dwt3_inv80<<<2000, 256, 0, stream>>>(bands, out);
}